// Round 19
// baseline (58.639 us; speedup 1.0000x reference)
//
#include <hip/hip_runtime.h>
#include <hip/hip_bf16.h>

#define N_NODES 4096
#define F_IN 512
#define FHD 64
#define H_HEADS 8
#define C_OUT 512   /* H*FH */
#define ALPHA 0.2f
#define MAXE 192
#define MAXE_P 200
#define GEMM_BLOCKS 512

typedef __attribute__((ext_vector_type(8))) short bf16x8;
typedef __attribute__((ext_vector_type(4))) float f32x4;

static __device__ __forceinline__ unsigned short f2bf(float f) {
  __hip_bfloat16 h = __float2bfloat16(f);
  union { __hip_bfloat16 h; unsigned short u; } cvt;
  cvt.h = h;
  return cvt.u;
}

// ---------------------------------------------------------------------------
// conv: 64 blocks, W[h][f][o] f32 -> WbT[h][o][f] bf16 (colsum zeroed by
// hipMemsetAsync in kernel_launch).
// ---------------------------------------------------------------------------
__global__ __launch_bounds__(256) void conv_kernel(
    const float* __restrict__ W, unsigned short* __restrict__ WbT) {
  __shared__ float sT[64][65];
  const int bid = blockIdx.x;
  const int tid = threadIdx.x;
  const int fblk = bid & 7, h = bid >> 3;
#pragma unroll
  for (int i = 0; i < 16; ++i) {
    int idx = tid + i * 256;
    int f = idx >> 6, o = idx & 63;
    sT[f][o] = W[((size_t)h * F_IN + fblk * 64 + f) * FHD + o];
  }
  __syncthreads();
#pragma unroll
  for (int i = 0; i < 16; ++i) {
    int idx = tid + i * 256;
    int o = idx >> 6, f = idx & 63;
    WbT[(size_t)h * FHD * F_IN + (size_t)o * F_IN + fblk * 64 + f] =
        f2bf(sT[f][o]);
  }
}

// ---------------------------------------------------------------------------
// gemm_scan: blocks [0,4096) = A-row CSR scan (FIRST in dispatch order so
// the HBM A-stream saturates from t=0); blocks [4096,4608) = MFMA GEMM
// (R14-proven internals: BK=64, dbuf, in-staging f32->bf16 cvt).
// ---------------------------------------------------------------------------
__global__ __launch_bounds__(256) void gemm_scan_kernel(
    const float* __restrict__ X, const unsigned short* __restrict__ WbT,
    const float* __restrict__ a_self, const float* __restrict__ a_neigh,
    const float* __restrict__ A,
    unsigned short* __restrict__ featsb,
    float* __restrict__ s_self, float* __restrict__ s_neigh,
    float* __restrict__ colsum,
    unsigned short* __restrict__ edges, int* __restrict__ degs) {
  __shared__ unsigned short sX[2][64 * 72];
  __shared__ unsigned short sW[2][64 * 72];
  __shared__ float sred[4][64];
  const int bid = blockIdx.x;
  const int tid = threadIdx.x;
  const int wid = tid >> 6, lane = tid & 63;

  if (bid < N_NODES) {
    // ---- scan path: CSR build for row i
    const int i = bid;
    int* wave_tot = reinterpret_cast<int*>(&sred[0][0]);
    const float4* __restrict__ Arow4 =
        reinterpret_cast<const float4*>(A + (size_t)i * N_NODES);
    float4 v[4];
#pragma unroll
    for (int q = 0; q < 4; ++q) v[q] = Arow4[tid * 4 + q];
    int mask16 = 0;
#pragma unroll
    for (int q = 0; q < 4; ++q) {
      mask16 |= (v[q].x != 0.f) ? (1 << (q * 4 + 0)) : 0;
      mask16 |= (v[q].y != 0.f) ? (1 << (q * 4 + 1)) : 0;
      mask16 |= (v[q].z != 0.f) ? (1 << (q * 4 + 2)) : 0;
      mask16 |= (v[q].w != 0.f) ? (1 << (q * 4 + 3)) : 0;
    }
    int cnt = __popc(mask16);
    int inc = cnt;
#pragma unroll
    for (int s = 1; s < 64; s <<= 1) {
      int t = __shfl_up(inc, s, 64);
      if (lane >= s) inc += t;
    }
    if (lane == 63) wave_tot[wid] = inc;
    __syncthreads();
    int wprefix = 0, tot = 0;
#pragma unroll
    for (int w = 0; w < 4; ++w) {
      int t = wave_tot[w];
      if (w < wid) wprefix += t;
      tot += t;
    }
    int pos = wprefix + inc - cnt;
    const int jbase = tid * 16;
    unsigned short* __restrict__ erow = edges + (size_t)i * MAXE;
    while (mask16) {
      int k = __ffs(mask16) - 1;
      mask16 &= mask16 - 1;
      if (pos < MAXE) erow[pos] = (unsigned short)(jbase + k);
      ++pos;
    }
    if (tid == 0) degs[i] = tot < MAXE ? tot : MAXE;
    return;
  }

  // ---- GEMM path
  const int g = bid - N_NODES;
  const int h = g >> 6;
  const int n0 = (g & 63) * 64;
  const int l15 = lane & 15, l4 = lane >> 4;

  const int row = tid >> 2, seg = (tid & 3) * 16;
  const float* xsrc = X + (size_t)(n0 + row) * F_IN + seg;
  const unsigned short* wsrc = WbT + ((size_t)h * FHD + row) * F_IN + seg;
  const int soff = row * 72 + seg;

  f32x4 acc[4];
#pragma unroll
  for (int j = 0; j < 4; ++j) acc[j] = (f32x4){0.f, 0.f, 0.f, 0.f};

  {
    float4 xa = *(const float4*)(xsrc);
    float4 xb = *(const float4*)(xsrc + 4);
    float4 xc = *(const float4*)(xsrc + 8);
    float4 xd = *(const float4*)(xsrc + 12);
    bf16x8 p0, p1;
    p0[0] = f2bf(xa.x); p0[1] = f2bf(xa.y); p0[2] = f2bf(xa.z); p0[3] = f2bf(xa.w);
    p0[4] = f2bf(xb.x); p0[5] = f2bf(xb.y); p0[6] = f2bf(xb.z); p0[7] = f2bf(xb.w);
    p1[0] = f2bf(xc.x); p1[1] = f2bf(xc.y); p1[2] = f2bf(xc.z); p1[3] = f2bf(xc.w);
    p1[4] = f2bf(xd.x); p1[5] = f2bf(xd.y); p1[6] = f2bf(xd.z); p1[7] = f2bf(xd.w);
    *(bf16x8*)&sX[0][soff] = p0;
    *(bf16x8*)&sX[0][soff + 8] = p1;
    *(bf16x8*)&sW[0][soff] = *(const bf16x8*)(wsrc);
    *(bf16x8*)&sW[0][soff + 8] = *(const bf16x8*)(wsrc + 8);
  }
  __syncthreads();

  int cur = 0;
  for (int s = 0; s < 8; ++s) {
    float4 xa, xb, xc, xd;
    bf16x8 pw0, pw1;
    const bool pf = (s < 7);
    if (pf) {
      const int k = (s + 1) * 64;
      xa = *(const float4*)(xsrc + k);
      xb = *(const float4*)(xsrc + k + 4);
      xc = *(const float4*)(xsrc + k + 8);
      xd = *(const float4*)(xsrc + k + 12);
      pw0 = *(const bf16x8*)(wsrc + k);
      pw1 = *(const bf16x8*)(wsrc + k + 8);
    }
#pragma unroll
    for (int kk = 0; kk < 2; ++kk) {
      bf16x8 a = *(const bf16x8*)&sX[cur][(wid * 16 + l15) * 72 + kk * 32 + l4 * 8];
#pragma unroll
      for (int tn = 0; tn < 4; ++tn) {
        bf16x8 b = *(const bf16x8*)&sW[cur][(tn * 16 + l15) * 72 + kk * 32 + l4 * 8];
        acc[tn] =
            __builtin_amdgcn_mfma_f32_16x16x32_bf16(a, b, acc[tn], 0, 0, 0);
      }
    }
    if (pf) {
      bf16x8 p0, p1;
      p0[0] = f2bf(xa.x); p0[1] = f2bf(xa.y); p0[2] = f2bf(xa.z); p0[3] = f2bf(xa.w);
      p0[4] = f2bf(xb.x); p0[5] = f2bf(xb.y); p0[6] = f2bf(xb.z); p0[7] = f2bf(xb.w);
      p1[0] = f2bf(xc.x); p1[1] = f2bf(xc.y); p1[2] = f2bf(xc.z); p1[3] = f2bf(xc.w);
      p1[4] = f2bf(xd.x); p1[5] = f2bf(xd.y); p1[6] = f2bf(xd.z); p1[7] = f2bf(xd.w);
      *(bf16x8*)&sX[cur ^ 1][soff] = p0;
      *(bf16x8*)&sX[cur ^ 1][soff + 8] = p1;
      *(bf16x8*)&sW[cur ^ 1][soff] = pw0;
      *(bf16x8*)&sW[cur ^ 1][soff + 8] = pw1;
      __syncthreads();
      cur ^= 1;
    }
  }

  float aS[4], aN[4];
#pragma unroll
  for (int tn = 0; tn < 4; ++tn) {
    aS[tn] = a_self[h * FHD + tn * 16 + l15];
    aN[tn] = a_neigh[h * FHD + tn * 16 + l15];
  }
#pragma unroll
  for (int r = 0; r < 4; ++r) {
    const int grow = n0 + wid * 16 + l4 * 4 + r;
#pragma unroll
    for (int tn = 0; tn < 4; ++tn)
      featsb[(size_t)grow * C_OUT + h * FHD + tn * 16 + l15] =
          f2bf(acc[tn][r]);
    float ps = 0.f, pn = 0.f;
#pragma unroll
    for (int tn = 0; tn < 4; ++tn) {
      float v = acc[tn][r];
      ps = fmaf(v, aS[tn], ps);
      pn = fmaf(v, aN[tn], pn);
    }
#pragma unroll
    for (int sh = 1; sh < 16; sh <<= 1) {
      ps += __shfl_xor(ps, sh, 64);
      pn += __shfl_xor(pn, sh, 64);
    }
    if (l15 == 0) {
      s_self[grow * 8 + h] = ps;
      s_neigh[grow * 8 + h] = pn;
    }
  }

  float psum[4];
#pragma unroll
  for (int tn = 0; tn < 4; ++tn) {
    float s = acc[tn][0] + acc[tn][1] + acc[tn][2] + acc[tn][3];
    s += __shfl_xor(s, 16, 64);
    s += __shfl_xor(s, 32, 64);
    psum[tn] = s;
  }
  __syncthreads();
  if (l4 == 0) {
#pragma unroll
    for (int tn = 0; tn < 4; ++tn) sred[wid][tn * 16 + l15] = psum[tn];
  }
  __syncthreads();
  if (tid < 64) {
    float s = sred[0][tid] + sred[1][tid] + sred[2][tid] + sred[3][tid];
    atomicAdd(&colsum[h * FHD + tid], s);
  }
}

// ---------------------------------------------------------------------------
// attn v10: R18 structure + fused logits/softmax. Each head-wave computes
// its own logits into 3 REGISTER slots (deg<=192, static indexing), max/sum
// reduces, writes s_w once — removes phase-1's barrier + deg*8 scattered LDS
// writes + one full s_w pass. Gather: dot2 edge-pairs (R18-proven).
// ---------------------------------------------------------------------------
__global__ __launch_bounds__(256) void attn_kernel(
    const unsigned short* __restrict__ edges, const int* __restrict__ degs,
    const unsigned short* __restrict__ featsb,
    const float* __restrict__ s_self, const float* __restrict__ s_neigh,
    const float* __restrict__ colsum, const float* __restrict__ bias,
    float* __restrict__ out) {
  const int i = blockIdx.x;
  const int tid = threadIdx.x;
  const int wid = tid >> 6, lane = tid & 63;
  __shared__ int s_idx[MAXE];
  __shared__ int s_off[MAXE];
  __shared__ float s_w[H_HEADS][MAXE_P];
  __shared__ float sh_self[8];
  __shared__ float sh_e0[8], sh_invZ[8];
  __shared__ float s_part[3][64][9];

  const int deg = degs[i];
  if (tid < 8) sh_self[tid] = s_self[i * 8 + tid];
  if (tid < deg) {
    int j = edges[(size_t)i * MAXE + tid];
    s_idx[tid] = j;
    s_off[tid] = j << 10;
  }
  __syncthreads();

  // Fused logits + softmax stats; wave wid owns heads 2wid, 2wid+1.
  // deg <= 192 -> exactly 3 lane-strided slots, fully static.
  const int e0i = lane, e1i = lane + 64, e2i = lane + 128;
#pragma unroll
  for (int p = 0; p < 2; ++p) {
    const int h = wid * 2 + p;
    const float selfh = sh_self[h];
    float v0 = -1e30f, v1 = -1e30f, v2 = -1e30f;
    if (e0i < deg) {
      float l = selfh + s_neigh[s_idx[e0i] * 8 + h];
      v0 = l > 0.f ? l : ALPHA * l;
    }
    if (e1i < deg) {
      float l = selfh + s_neigh[s_idx[e1i] * 8 + h];
      v1 = l > 0.f ? l : ALPHA * l;
    }
    if (e2i < deg) {
      float l = selfh + s_neigh[s_idx[e2i] * 8 + h];
      v2 = l > 0.f ? l : ALPHA * l;
    }
    float m = fmaxf(fmaxf(v0, v1), v2);
#pragma unroll
    for (int s = 32; s > 0; s >>= 1) m = fmaxf(m, __shfl_xor(m, s, 64));
    m = fmaxf(m, 0.0f);  // non-edge dense entries are exactly 0
    float e0 = __expf(-m);
    float zs = 0.f;
    if (e0i < deg) {
      float w = __expf(v0 - m);
      s_w[h][e0i] = w - e0;
      zs += w;
    }
    if (e1i < deg) {
      float w = __expf(v1 - m);
      s_w[h][e1i] = w - e0;
      zs += w;
    }
    if (e2i < deg) {
      float w = __expf(v2 - m);
      s_w[h][e2i] = w - e0;
      zs += w;
    }
#pragma unroll
    for (int s = 32; s > 0; s >>= 1) zs += __shfl_xor(zs, s, 64);
    if (lane == 0) {
      sh_e0[h] = e0;
      sh_invZ[h] = 1.0f / (zs + (float)(N_NODES - deg) * e0);
    }
  }
  __syncthreads();

  // Gather: co = column oct (8 cols, 16B), wave = edge quarter, edge pairs.
  const int co = lane;
  const int q = wid;
  const int h = co >> 3;
  const int dq = (deg + 3) >> 2;
  const int ebeg = q * dq;
  const int eend = (ebeg + dq) < deg ? (ebeg + dq) : deg;
  const char* __restrict__ fbase =
      reinterpret_cast<const char*>(featsb) + co * 16;
  float a0 = 0.f, a1 = 0.f, a2 = 0.f, a3 = 0.f;
  float a4 = 0.f, a5 = 0.f, a6 = 0.f, a7 = 0.f;
  float c0 = 0.f, c1 = 0.f, c2 = 0.f, c3 = 0.f;
  float c4 = 0.f, c5 = 0.f, c6 = 0.f, c7 = 0.f;

#define DOT2(accv, pair, wp) \
  asm("v_dot2_f32_bf16 %0, %1, %2, %0" : "+v"(accv) : "v"(pair), "v"(wp))

  int e = ebeg;
  for (; e + 3 < eend; e += 4) {
    float w0 = s_w[h][e], w1 = s_w[h][e + 1];
    float w2 = s_w[h][e + 2], w3 = s_w[h][e + 3];
    unsigned wp01, wp23;
    asm("v_cvt_pk_bf16_f32 %0, %1, %2" : "=v"(wp01) : "v"(w0), "v"(w1));
    asm("v_cvt_pk_bf16_f32 %0, %1, %2" : "=v"(wp23) : "v"(w2), "v"(w3));
    int o0 = s_off[e], o1 = s_off[e + 1];
    int o2 = s_off[e + 2], o3 = s_off[e + 3];
    uint4 u0 = *reinterpret_cast<const uint4*>(fbase + o0);
    uint4 u1 = *reinterpret_cast<const uint4*>(fbase + o1);
    uint4 u2 = *reinterpret_cast<const uint4*>(fbase + o2);
    uint4 u3 = *reinterpret_cast<const uint4*>(fbase + o3);
    unsigned plo, phi;
    plo = __builtin_amdgcn_perm(u1.x, u0.x, 0x05040100u);
    phi = __builtin_amdgcn_perm(u1.x, u0.x, 0x07060302u);
    DOT2(a0, plo, wp01); DOT2(a1, phi, wp01);
    plo = __builtin_amdgcn_perm(u1.y, u0.y, 0x05040100u);
    phi = __builtin_amdgcn_perm(u1.y, u0.y, 0x07060302u);
    DOT2(a2, plo, wp01); DOT2(a3, phi, wp01);
    plo = __builtin_amdgcn_perm(u1.z, u0.z, 0x05040100u);
    phi = __builtin_amdgcn_perm(u1.z, u0.z, 0x07060302u);
    DOT2(a4, plo, wp01); DOT2(a5, phi, wp01);
    plo = __builtin_amdgcn_perm(u1.w, u0.w, 0x05040100u);
    phi = __builtin_amdgcn_perm(u1.w, u0.w, 0x07060302u);
    DOT2(a6, plo, wp01); DOT2(a7, phi, wp01);
    plo = __builtin_amdgcn_perm(u3.x, u2.x, 0x05040100u);
    phi = __builtin_amdgcn_perm(u3.x, u2.x, 0x07060302u);
    DOT2(c0, plo, wp23); DOT2(c1, phi, wp23);
    plo = __builtin_amdgcn_perm(u3.y, u2.y, 0x05040100u);
    phi = __builtin_amdgcn_perm(u3.y, u2.y, 0x07060302u);
    DOT2(c2, plo, wp23); DOT2(c3, phi, wp23);
    plo = __builtin_amdgcn_perm(u3.z, u2.z, 0x05040100u);
    phi = __builtin_amdgcn_perm(u3.z, u2.z, 0x07060302u);
    DOT2(c4, plo, wp23); DOT2(c5, phi, wp23);
    plo = __builtin_amdgcn_perm(u3.w, u2.w, 0x05040100u);
    phi = __builtin_amdgcn_perm(u3.w, u2.w, 0x07060302u);
    DOT2(c6, plo, wp23); DOT2(c7, phi, wp23);
  }
  for (; e < eend; ++e) {  // scalar tail (exact f32 path)
    float w0 = s_w[h][e];
    uint4 u0 = *reinterpret_cast<const uint4*>(fbase + s_off[e]);
    a0 = fmaf(w0, __uint_as_float(u0.x << 16), a0);
    a1 = fmaf(w0, __uint_as_float(u0.x & 0xFFFF0000u), a1);
    a2 = fmaf(w0, __uint_as_float(u0.y << 16), a2);
    a3 = fmaf(w0, __uint_as_float(u0.y & 0xFFFF0000u), a3);
    a4 = fmaf(w0, __uint_as_float(u0.z << 16), a4);
    a5 = fmaf(w0, __uint_as_float(u0.z & 0xFFFF0000u), a5);
    a6 = fmaf(w0, __uint_as_float(u0.w << 16), a6);
    a7 = fmaf(w0, __uint_as_float(u0.w & 0xFFFF0000u), a7);
  }
#undef DOT2
  a0 += c0; a1 += c1; a2 += c2; a3 += c3;
  a4 += c4; a5 += c5; a6 += c6; a7 += c7;

  if (q > 0) {
    float* p = &s_part[q - 1][co][0];
    p[0] = a0; p[1] = a1; p[2] = a2; p[3] = a3;
    p[4] = a4; p[5] = a5; p[6] = a6; p[7] = a7;
  }
  __syncthreads();
  if (q == 0) {
#pragma unroll
    for (int pp = 0; pp < 3; ++pp) {
      const float* p = &s_part[pp][co][0];
      a0 += p[0]; a1 += p[1]; a2 += p[2]; a3 += p[3];
      a4 += p[4]; a5 += p[5]; a6 += p[6]; a7 += p[7];
    }
    const float e0 = sh_e0[h], invZ = sh_invZ[h];
    const float4 cs0 = *reinterpret_cast<const float4*>(&colsum[co * 8]);
    const float4 cs1 = *reinterpret_cast<const float4*>(&colsum[co * 8 + 4]);
    const float4 bb0 = *reinterpret_cast<const float4*>(&bias[co * 8]);
    const float4 bb1 = *reinterpret_cast<const float4*>(&bias[co * 8 + 4]);
    f32x4 o0, o1;
    float v;
    v = (a0 + e0 * cs0.x) * invZ + bb0.x; o0.x = v > 0.f ? v : 0.f;
    v = (a1 + e0 * cs0.y) * invZ + bb0.y; o0.y = v > 0.f ? v : 0.f;
    v = (a2 + e0 * cs0.z) * invZ + bb0.z; o0.z = v > 0.f ? v : 0.f;
    v = (a3 + e0 * cs0.w) * invZ + bb0.w; o0.w = v > 0.f ? v : 0.f;
    v = (a4 + e0 * cs1.x) * invZ + bb1.x; o1.x = v > 0.f ? v : 0.f;
    v = (a5 + e0 * cs1.y) * invZ + bb1.y; o1.y = v > 0.f ? v : 0.f;
    v = (a6 + e0 * cs1.z) * invZ + bb1.z; o1.z = v > 0.f ? v : 0.f;
    v = (a7 + e0 * cs1.w) * invZ + bb1.w; o1.w = v > 0.f ? v : 0.f;
    f32x4* dst = reinterpret_cast<f32x4*>(&out[(size_t)i * C_OUT + co * 8]);
    __builtin_nontemporal_store(o0, dst);
    __builtin_nontemporal_store(o1, dst + 1);
  }
}

extern "C" void kernel_launch(void* const* d_in, const int* in_sizes, int n_in,
                              void* d_out, int out_size, void* d_ws, size_t ws_size,
                              hipStream_t stream) {
  const float* X = (const float*)d_in[0];
  const float* A = (const float*)d_in[1];
  const float* W = (const float*)d_in[2];
  const float* a_self = (const float*)d_in[3];
  const float* a_neigh = (const float*)d_in[4];
  const float* b = (const float*)d_in[5];
  float* out = (float*)d_out;

  char* ws = (char*)d_ws;
  unsigned short* featsb = (unsigned short*)ws;               // 4 MB
  char* p = ws + (size_t)N_NODES * C_OUT * 2;
  float* s_self = (float*)p;  p += N_NODES * H_HEADS * 4;     // 128 KB
  float* s_neigh = (float*)p; p += N_NODES * H_HEADS * 4;     // 128 KB
  float* colsum = (float*)p;  p += C_OUT * 4;                 // 2 KB
  int* degs = (int*)p;        p += N_NODES * 4;               // 16 KB
  unsigned short* edges = (unsigned short*)p;
  p += (size_t)N_NODES * MAXE * 2;                            // 1.5 MB
  unsigned short* WbT = (unsigned short*)p;                   // 512 KB

  hipMemsetAsync(colsum, 0, C_OUT * 4, stream);
  conv_kernel<<<64, 256, 0, stream>>>(W, WbT);
  gemm_scan_kernel<<<N_NODES + GEMM_BLOCKS, 256, 0, stream>>>(
      X, WbT, a_self, a_neigh, A, featsb, s_self, s_neigh, colsum, edges,
      degs);
  attn_kernel<<<N_NODES, 256, 0, stream>>>(edges, degs, featsb, s_self,
                                           s_neigh, colsum, b, out);
}

// Round 20
// 54.827 us; speedup vs baseline: 1.0695x; 1.0695x over previous
//
#include <hip/hip_runtime.h>
#include <hip/hip_bf16.h>

#define N_NODES 4096
#define F_IN 512
#define FHD 64
#define H_HEADS 8
#define C_OUT 512   /* H*FH */
#define ALPHA 0.2f
#define MAXE 192
#define MAXE_P 200
#define GEMM_BLOCKS 512

typedef __attribute__((ext_vector_type(8))) short bf16x8;
typedef __attribute__((ext_vector_type(4))) float f32x4;

static __device__ __forceinline__ unsigned short f2bf(float f) {
  __hip_bfloat16 h = __float2bfloat16(f);
  union { __hip_bfloat16 h; unsigned short u; } cvt;
  cvt.h = h;
  return cvt.u;
}

// ---------------------------------------------------------------------------
// conv: 64 blocks, W[h][f][o] f32 -> WbT[h][o][f] bf16 (colsum zeroed by
// hipMemsetAsync in kernel_launch).
// ---------------------------------------------------------------------------
__global__ __launch_bounds__(256) void conv_kernel(
    const float* __restrict__ W, unsigned short* __restrict__ WbT) {
  __shared__ float sT[64][65];
  const int bid = blockIdx.x;
  const int tid = threadIdx.x;
  const int fblk = bid & 7, h = bid >> 3;
#pragma unroll
  for (int i = 0; i < 16; ++i) {
    int idx = tid + i * 256;
    int f = idx >> 6, o = idx & 63;
    sT[f][o] = W[((size_t)h * F_IN + fblk * 64 + f) * FHD + o];
  }
  __syncthreads();
#pragma unroll
  for (int i = 0; i < 16; ++i) {
    int idx = tid + i * 256;
    int o = idx >> 6, f = idx & 63;
    WbT[(size_t)h * FHD * F_IN + (size_t)o * F_IN + fblk * 64 + f] =
        f2bf(sT[f][o]);
  }
}

// ---------------------------------------------------------------------------
// gemm_scan (R18 ordering restored): blocks [0,512) = MFMA GEMM resident
// from t=0; blocks [512,4608) = A-row CSR scan streaming alongside
// (R8-proven overlap; scan-first serialized them — R19 regression).
// ---------------------------------------------------------------------------
__global__ __launch_bounds__(256) void gemm_scan_kernel(
    const float* __restrict__ X, const unsigned short* __restrict__ WbT,
    const float* __restrict__ a_self, const float* __restrict__ a_neigh,
    const float* __restrict__ A,
    unsigned short* __restrict__ featsb,
    float* __restrict__ s_self, float* __restrict__ s_neigh,
    float* __restrict__ colsum,
    unsigned short* __restrict__ edges, int* __restrict__ degs) {
  __shared__ unsigned short sX[2][64 * 72];
  __shared__ unsigned short sW[2][64 * 72];
  __shared__ float sred[4][64];
  const int bid = blockIdx.x;
  const int tid = threadIdx.x;
  const int wid = tid >> 6, lane = tid & 63;

  if (bid >= GEMM_BLOCKS) {
    // ---- scan path: CSR build for row i
    const int i = bid - GEMM_BLOCKS;
    int* wave_tot = reinterpret_cast<int*>(&sred[0][0]);
    const float4* __restrict__ Arow4 =
        reinterpret_cast<const float4*>(A + (size_t)i * N_NODES);
    float4 v[4];
#pragma unroll
    for (int q = 0; q < 4; ++q) v[q] = Arow4[tid * 4 + q];
    int mask16 = 0;
#pragma unroll
    for (int q = 0; q < 4; ++q) {
      mask16 |= (v[q].x != 0.f) ? (1 << (q * 4 + 0)) : 0;
      mask16 |= (v[q].y != 0.f) ? (1 << (q * 4 + 1)) : 0;
      mask16 |= (v[q].z != 0.f) ? (1 << (q * 4 + 2)) : 0;
      mask16 |= (v[q].w != 0.f) ? (1 << (q * 4 + 3)) : 0;
    }
    int cnt = __popc(mask16);
    int inc = cnt;
#pragma unroll
    for (int s = 1; s < 64; s <<= 1) {
      int t = __shfl_up(inc, s, 64);
      if (lane >= s) inc += t;
    }
    if (lane == 63) wave_tot[wid] = inc;
    __syncthreads();
    int wprefix = 0, tot = 0;
#pragma unroll
    for (int w = 0; w < 4; ++w) {
      int t = wave_tot[w];
      if (w < wid) wprefix += t;
      tot += t;
    }
    int pos = wprefix + inc - cnt;
    const int jbase = tid * 16;
    unsigned short* __restrict__ erow = edges + (size_t)i * MAXE;
    while (mask16) {
      int k = __ffs(mask16) - 1;
      mask16 &= mask16 - 1;
      if (pos < MAXE) erow[pos] = (unsigned short)(jbase + k);
      ++pos;
    }
    if (tid == 0) degs[i] = tot < MAXE ? tot : MAXE;
    return;
  }

  // ---- GEMM path
  const int h = bid >> 6;
  const int n0 = (bid & 63) * 64;
  const int l15 = lane & 15, l4 = lane >> 4;

  const int row = tid >> 2, seg = (tid & 3) * 16;
  const float* xsrc = X + (size_t)(n0 + row) * F_IN + seg;
  const unsigned short* wsrc = WbT + ((size_t)h * FHD + row) * F_IN + seg;
  const int soff = row * 72 + seg;

  f32x4 acc[4];
#pragma unroll
  for (int j = 0; j < 4; ++j) acc[j] = (f32x4){0.f, 0.f, 0.f, 0.f};

  {
    float4 xa = *(const float4*)(xsrc);
    float4 xb = *(const float4*)(xsrc + 4);
    float4 xc = *(const float4*)(xsrc + 8);
    float4 xd = *(const float4*)(xsrc + 12);
    bf16x8 p0, p1;
    p0[0] = f2bf(xa.x); p0[1] = f2bf(xa.y); p0[2] = f2bf(xa.z); p0[3] = f2bf(xa.w);
    p0[4] = f2bf(xb.x); p0[5] = f2bf(xb.y); p0[6] = f2bf(xb.z); p0[7] = f2bf(xb.w);
    p1[0] = f2bf(xc.x); p1[1] = f2bf(xc.y); p1[2] = f2bf(xc.z); p1[3] = f2bf(xc.w);
    p1[4] = f2bf(xd.x); p1[5] = f2bf(xd.y); p1[6] = f2bf(xd.z); p1[7] = f2bf(xd.w);
    *(bf16x8*)&sX[0][soff] = p0;
    *(bf16x8*)&sX[0][soff + 8] = p1;
    *(bf16x8*)&sW[0][soff] = *(const bf16x8*)(wsrc);
    *(bf16x8*)&sW[0][soff + 8] = *(const bf16x8*)(wsrc + 8);
  }
  __syncthreads();

  int cur = 0;
  for (int s = 0; s < 8; ++s) {
    float4 xa, xb, xc, xd;
    bf16x8 pw0, pw1;
    const bool pf = (s < 7);
    if (pf) {
      const int k = (s + 1) * 64;
      xa = *(const float4*)(xsrc + k);
      xb = *(const float4*)(xsrc + k + 4);
      xc = *(const float4*)(xsrc + k + 8);
      xd = *(const float4*)(xsrc + k + 12);
      pw0 = *(const bf16x8*)(wsrc + k);
      pw1 = *(const bf16x8*)(wsrc + k + 8);
    }
#pragma unroll
    for (int kk = 0; kk < 2; ++kk) {
      bf16x8 a = *(const bf16x8*)&sX[cur][(wid * 16 + l15) * 72 + kk * 32 + l4 * 8];
#pragma unroll
      for (int tn = 0; tn < 4; ++tn) {
        bf16x8 b = *(const bf16x8*)&sW[cur][(tn * 16 + l15) * 72 + kk * 32 + l4 * 8];
        acc[tn] =
            __builtin_amdgcn_mfma_f32_16x16x32_bf16(a, b, acc[tn], 0, 0, 0);
      }
    }
    if (pf) {
      bf16x8 p0, p1;
      p0[0] = f2bf(xa.x); p0[1] = f2bf(xa.y); p0[2] = f2bf(xa.z); p0[3] = f2bf(xa.w);
      p0[4] = f2bf(xb.x); p0[5] = f2bf(xb.y); p0[6] = f2bf(xb.z); p0[7] = f2bf(xb.w);
      p1[0] = f2bf(xc.x); p1[1] = f2bf(xc.y); p1[2] = f2bf(xc.z); p1[3] = f2bf(xc.w);
      p1[4] = f2bf(xd.x); p1[5] = f2bf(xd.y); p1[6] = f2bf(xd.z); p1[7] = f2bf(xd.w);
      *(bf16x8*)&sX[cur ^ 1][soff] = p0;
      *(bf16x8*)&sX[cur ^ 1][soff + 8] = p1;
      *(bf16x8*)&sW[cur ^ 1][soff] = pw0;
      *(bf16x8*)&sW[cur ^ 1][soff + 8] = pw1;
      __syncthreads();
      cur ^= 1;
    }
  }

  float aS[4], aN[4];
#pragma unroll
  for (int tn = 0; tn < 4; ++tn) {
    aS[tn] = a_self[h * FHD + tn * 16 + l15];
    aN[tn] = a_neigh[h * FHD + tn * 16 + l15];
  }
#pragma unroll
  for (int r = 0; r < 4; ++r) {
    const int grow = n0 + wid * 16 + l4 * 4 + r;
#pragma unroll
    for (int tn = 0; tn < 4; ++tn)
      featsb[(size_t)grow * C_OUT + h * FHD + tn * 16 + l15] =
          f2bf(acc[tn][r]);
    float ps = 0.f, pn = 0.f;
#pragma unroll
    for (int tn = 0; tn < 4; ++tn) {
      float v = acc[tn][r];
      ps = fmaf(v, aS[tn], ps);
      pn = fmaf(v, aN[tn], pn);
    }
#pragma unroll
    for (int sh = 1; sh < 16; sh <<= 1) {
      ps += __shfl_xor(ps, sh, 64);
      pn += __shfl_xor(pn, sh, 64);
    }
    if (l15 == 0) {
      s_self[grow * 8 + h] = ps;
      s_neigh[grow * 8 + h] = pn;
    }
  }

  float psum[4];
#pragma unroll
  for (int tn = 0; tn < 4; ++tn) {
    float s = acc[tn][0] + acc[tn][1] + acc[tn][2] + acc[tn][3];
    s += __shfl_xor(s, 16, 64);
    s += __shfl_xor(s, 32, 64);
    psum[tn] = s;
  }
  __syncthreads();
  if (l4 == 0) {
#pragma unroll
    for (int tn = 0; tn < 4; ++tn) sred[wid][tn * 16 + l15] = psum[tn];
  }
  __syncthreads();
  if (tid < 64) {
    float s = sred[0][tid] + sred[1][tid] + sred[2][tid] + sred[3][tid];
    atomicAdd(&colsum[h * FHD + tid], s);
  }
}

// ---------------------------------------------------------------------------
// attn v10 (R19 verbatim): fused logits+softmax into 3 register slots per
// head-wave; gather = dot2 edge-pairs; NT out stores.
// ---------------------------------------------------------------------------
__global__ __launch_bounds__(256) void attn_kernel(
    const unsigned short* __restrict__ edges, const int* __restrict__ degs,
    const unsigned short* __restrict__ featsb,
    const float* __restrict__ s_self, const float* __restrict__ s_neigh,
    const float* __restrict__ colsum, const float* __restrict__ bias,
    float* __restrict__ out) {
  const int i = blockIdx.x;
  const int tid = threadIdx.x;
  const int wid = tid >> 6, lane = tid & 63;
  __shared__ int s_idx[MAXE];
  __shared__ int s_off[MAXE];
  __shared__ float s_w[H_HEADS][MAXE_P];
  __shared__ float sh_self[8];
  __shared__ float sh_e0[8], sh_invZ[8];
  __shared__ float s_part[3][64][9];

  const int deg = degs[i];
  if (tid < 8) sh_self[tid] = s_self[i * 8 + tid];
  if (tid < deg) {
    int j = edges[(size_t)i * MAXE + tid];
    s_idx[tid] = j;
    s_off[tid] = j << 10;
  }
  __syncthreads();

  const int e0i = lane, e1i = lane + 64, e2i = lane + 128;
#pragma unroll
  for (int p = 0; p < 2; ++p) {
    const int h = wid * 2 + p;
    const float selfh = sh_self[h];
    float v0 = -1e30f, v1 = -1e30f, v2 = -1e30f;
    if (e0i < deg) {
      float l = selfh + s_neigh[s_idx[e0i] * 8 + h];
      v0 = l > 0.f ? l : ALPHA * l;
    }
    if (e1i < deg) {
      float l = selfh + s_neigh[s_idx[e1i] * 8 + h];
      v1 = l > 0.f ? l : ALPHA * l;
    }
    if (e2i < deg) {
      float l = selfh + s_neigh[s_idx[e2i] * 8 + h];
      v2 = l > 0.f ? l : ALPHA * l;
    }
    float m = fmaxf(fmaxf(v0, v1), v2);
#pragma unroll
    for (int s = 32; s > 0; s >>= 1) m = fmaxf(m, __shfl_xor(m, s, 64));
    m = fmaxf(m, 0.0f);  // non-edge dense entries are exactly 0
    float e0 = __expf(-m);
    float zs = 0.f;
    if (e0i < deg) {
      float w = __expf(v0 - m);
      s_w[h][e0i] = w - e0;
      zs += w;
    }
    if (e1i < deg) {
      float w = __expf(v1 - m);
      s_w[h][e1i] = w - e0;
      zs += w;
    }
    if (e2i < deg) {
      float w = __expf(v2 - m);
      s_w[h][e2i] = w - e0;
      zs += w;
    }
#pragma unroll
    for (int s = 32; s > 0; s >>= 1) zs += __shfl_xor(zs, s, 64);
    if (lane == 0) {
      sh_e0[h] = e0;
      sh_invZ[h] = 1.0f / (zs + (float)(N_NODES - deg) * e0);
    }
  }
  __syncthreads();

  const int co = lane;
  const int q = wid;
  const int h = co >> 3;
  const int dq = (deg + 3) >> 2;
  const int ebeg = q * dq;
  const int eend = (ebeg + dq) < deg ? (ebeg + dq) : deg;
  const char* __restrict__ fbase =
      reinterpret_cast<const char*>(featsb) + co * 16;
  float a0 = 0.f, a1 = 0.f, a2 = 0.f, a3 = 0.f;
  float a4 = 0.f, a5 = 0.f, a6 = 0.f, a7 = 0.f;
  float c0 = 0.f, c1 = 0.f, c2 = 0.f, c3 = 0.f;
  float c4 = 0.f, c5 = 0.f, c6 = 0.f, c7 = 0.f;

#define DOT2(accv, pair, wp) \
  asm("v_dot2_f32_bf16 %0, %1, %2, %0" : "+v"(accv) : "v"(pair), "v"(wp))

  int e = ebeg;
  for (; e + 3 < eend; e += 4) {
    float w0 = s_w[h][e], w1 = s_w[h][e + 1];
    float w2 = s_w[h][e + 2], w3 = s_w[h][e + 3];
    unsigned wp01, wp23;
    asm("v_cvt_pk_bf16_f32 %0, %1, %2" : "=v"(wp01) : "v"(w0), "v"(w1));
    asm("v_cvt_pk_bf16_f32 %0, %1, %2" : "=v"(wp23) : "v"(w2), "v"(w3));
    int o0 = s_off[e], o1 = s_off[e + 1];
    int o2 = s_off[e + 2], o3 = s_off[e + 3];
    uint4 u0 = *reinterpret_cast<const uint4*>(fbase + o0);
    uint4 u1 = *reinterpret_cast<const uint4*>(fbase + o1);
    uint4 u2 = *reinterpret_cast<const uint4*>(fbase + o2);
    uint4 u3 = *reinterpret_cast<const uint4*>(fbase + o3);
    unsigned plo, phi;
    plo = __builtin_amdgcn_perm(u1.x, u0.x, 0x05040100u);
    phi = __builtin_amdgcn_perm(u1.x, u0.x, 0x07060302u);
    DOT2(a0, plo, wp01); DOT2(a1, phi, wp01);
    plo = __builtin_amdgcn_perm(u1.y, u0.y, 0x05040100u);
    phi = __builtin_amdgcn_perm(u1.y, u0.y, 0x07060302u);
    DOT2(a2, plo, wp01); DOT2(a3, phi, wp01);
    plo = __builtin_amdgcn_perm(u1.z, u0.z, 0x05040100u);
    phi = __builtin_amdgcn_perm(u1.z, u0.z, 0x07060302u);
    DOT2(a4, plo, wp01); DOT2(a5, phi, wp01);
    plo = __builtin_amdgcn_perm(u1.w, u0.w, 0x05040100u);
    phi = __builtin_amdgcn_perm(u1.w, u0.w, 0x07060302u);
    DOT2(a6, plo, wp01); DOT2(a7, phi, wp01);
    plo = __builtin_amdgcn_perm(u3.x, u2.x, 0x05040100u);
    phi = __builtin_amdgcn_perm(u3.x, u2.x, 0x07060302u);
    DOT2(c0, plo, wp23); DOT2(c1, phi, wp23);
    plo = __builtin_amdgcn_perm(u3.y, u2.y, 0x05040100u);
    phi = __builtin_amdgcn_perm(u3.y, u2.y, 0x07060302u);
    DOT2(c2, plo, wp23); DOT2(c3, phi, wp23);
    plo = __builtin_amdgcn_perm(u3.z, u2.z, 0x05040100u);
    phi = __builtin_amdgcn_perm(u3.z, u2.z, 0x07060302u);
    DOT2(c4, plo, wp23); DOT2(c5, phi, wp23);
    plo = __builtin_amdgcn_perm(u3.w, u2.w, 0x05040100u);
    phi = __builtin_amdgcn_perm(u3.w, u2.w, 0x07060302u);
    DOT2(c6, plo, wp23); DOT2(c7, phi, wp23);
  }
  for (; e < eend; ++e) {  // scalar tail (exact f32 path)
    float w0 = s_w[h][e];
    uint4 u0 = *reinterpret_cast<const uint4*>(fbase + s_off[e]);
    a0 = fmaf(w0, __uint_as_float(u0.x << 16), a0);
    a1 = fmaf(w0, __uint_as_float(u0.x & 0xFFFF0000u), a1);
    a2 = fmaf(w0, __uint_as_float(u0.y << 16), a2);
    a3 = fmaf(w0, __uint_as_float(u0.y & 0xFFFF0000u), a3);
    a4 = fmaf(w0, __uint_as_float(u0.z << 16), a4);
    a5 = fmaf(w0, __uint_as_float(u0.z & 0xFFFF0000u), a5);
    a6 = fmaf(w0, __uint_as_float(u0.w << 16), a6);
    a7 = fmaf(w0, __uint_as_float(u0.w & 0xFFFF0000u), a7);
  }
#undef DOT2
  a0 += c0; a1 += c1; a2 += c2; a3 += c3;
  a4 += c4; a5 += c5; a6 += c6; a7 += c7;

  if (q > 0) {
    float* p = &s_part[q - 1][co][0];
    p[0] = a0; p[1] = a1; p[2] = a2; p[3] = a3;
    p[4] = a4; p[5] = a5; p[6] = a6; p[7] = a7;
  }
  __syncthreads();
  if (q == 0) {
#pragma unroll
    for (int pp = 0; pp < 3; ++pp) {
      const float* p = &s_part[pp][co][0];
      a0 += p[0]; a1 += p[1]; a2 += p[2]; a3 += p[3];
      a4 += p[4]; a5 += p[5]; a6 += p[6]; a7 += p[7];
    }
    const float e0 = sh_e0[h], invZ = sh_invZ[h];
    const float4 cs0 = *reinterpret_cast<const float4*>(&colsum[co * 8]);
    const float4 cs1 = *reinterpret_cast<const float4*>(&colsum[co * 8 + 4]);
    const float4 bb0 = *reinterpret_cast<const float4*>(&bias[co * 8]);
    const float4 bb1 = *reinterpret_cast<const float4*>(&bias[co * 8 + 4]);
    f32x4 o0, o1;
    float v;
    v = (a0 + e0 * cs0.x) * invZ + bb0.x; o0.x = v > 0.f ? v : 0.f;
    v = (a1 + e0 * cs0.y) * invZ + bb0.y; o0.y = v > 0.f ? v : 0.f;
    v = (a2 + e0 * cs0.z) * invZ + bb0.z; o0.z = v > 0.f ? v : 0.f;
    v = (a3 + e0 * cs0.w) * invZ + bb0.w; o0.w = v > 0.f ? v : 0.f;
    v = (a4 + e0 * cs1.x) * invZ + bb1.x; o1.x = v > 0.f ? v : 0.f;
    v = (a5 + e0 * cs1.y) * invZ + bb1.y; o1.y = v > 0.f ? v : 0.f;
    v = (a6 + e0 * cs1.z) * invZ + bb1.z; o1.z = v > 0.f ? v : 0.f;
    v = (a7 + e0 * cs1.w) * invZ + bb1.w; o1.w = v > 0.f ? v : 0.f;
    f32x4* dst = reinterpret_cast<f32x4*>(&out[(size_t)i * C_OUT + co * 8]);
    __builtin_nontemporal_store(o0, dst);
    __builtin_nontemporal_store(o1, dst + 1);
  }
}

extern "C" void kernel_launch(void* const* d_in, const int* in_sizes, int n_in,
                              void* d_out, int out_size, void* d_ws, size_t ws_size,
                              hipStream_t stream) {
  const float* X = (const float*)d_in[0];
  const float* A = (const float*)d_in[1];
  const float* W = (const float*)d_in[2];
  const float* a_self = (const float*)d_in[3];
  const float* a_neigh = (const float*)d_in[4];
  const float* b = (const float*)d_in[5];
  float* out = (float*)d_out;

  char* ws = (char*)d_ws;
  unsigned short* featsb = (unsigned short*)ws;               // 4 MB
  char* p = ws + (size_t)N_NODES * C_OUT * 2;
  float* s_self = (float*)p;  p += N_NODES * H_HEADS * 4;     // 128 KB
  float* s_neigh = (float*)p; p += N_NODES * H_HEADS * 4;     // 128 KB
  float* colsum = (float*)p;  p += C_OUT * 4;                 // 2 KB
  int* degs = (int*)p;        p += N_NODES * 4;               // 16 KB
  unsigned short* edges = (unsigned short*)p;
  p += (size_t)N_NODES * MAXE * 2;                            // 1.5 MB
  unsigned short* WbT = (unsigned short*)p;                   // 512 KB

  hipMemsetAsync(colsum, 0, C_OUT * 4, stream);
  conv_kernel<<<64, 256, 0, stream>>>(W, WbT);
  gemm_scan_kernel<<<GEMM_BLOCKS + N_NODES, 256, 0, stream>>>(
      X, WbT, a_self, a_neigh, A, featsb, s_self, s_neigh, colsum, edges,
      degs);
  attn_kernel<<<N_NODES, 256, 0, stream>>>(edges, degs, featsb, s_self,
                                           s_neigh, colsum, b, out);
}

// Round 21
// 50.433 us; speedup vs baseline: 1.1627x; 1.0871x over previous
//
#include <hip/hip_runtime.h>
#include <hip/hip_bf16.h>

#define N_NODES 4096
#define F_IN 512
#define FHD 64
#define H_HEADS 8
#define C_OUT 512   /* H*FH */
#define ALPHA 0.2f
#define MAXE 192
#define MAXE_P 200
#define GEMM_BLOCKS 512

typedef __attribute__((ext_vector_type(8))) short bf16x8;
typedef __attribute__((ext_vector_type(4))) float f32x4;

static __device__ __forceinline__ unsigned short f2bf(float f) {
  __hip_bfloat16 h = __float2bfloat16(f);
  union { __hip_bfloat16 h; unsigned short u; } cvt;
  cvt.h = h;
  return cvt.u;
}

// ---------------------------------------------------------------------------
// conv (R14/R18 verbatim): blocks [0,64) W transpose->bf16 | 64: zero colsum.
// ---------------------------------------------------------------------------
__global__ __launch_bounds__(256) void conv_kernel(
    const float* __restrict__ W, unsigned short* __restrict__ WbT,
    float* __restrict__ colsum) {
  __shared__ float sT[64][65];
  const int bid = blockIdx.x;
  const int tid = threadIdx.x;
  if (bid < 64) {
    const int fblk = bid & 7, h = bid >> 3;
#pragma unroll
    for (int i = 0; i < 16; ++i) {
      int idx = tid + i * 256;
      int f = idx >> 6, o = idx & 63;
      sT[f][o] = W[((size_t)h * F_IN + fblk * 64 + f) * FHD + o];
    }
    __syncthreads();
#pragma unroll
    for (int i = 0; i < 16; ++i) {
      int idx = tid + i * 256;
      int o = idx >> 6, f = idx & 63;
      WbT[(size_t)h * FHD * F_IN + (size_t)o * F_IN + fblk * 64 + f] =
          f2bf(sT[f][o]);
    }
  } else {
    colsum[tid] = 0.f;
    colsum[tid + 256] = 0.f;
  }
}

// ---------------------------------------------------------------------------
// gemm_scan (R14/R18 verbatim): blocks [0,512) MFMA GEMM (BK=64, dbuf,
// in-staging f32->bf16 cvt); blocks [512,4608) A-row CSR scan. Co-resident.
// ---------------------------------------------------------------------------
__global__ __launch_bounds__(256) void gemm_scan_kernel(
    const float* __restrict__ X, const unsigned short* __restrict__ WbT,
    const float* __restrict__ a_self, const float* __restrict__ a_neigh,
    const float* __restrict__ A,
    unsigned short* __restrict__ featsb,
    float* __restrict__ s_self, float* __restrict__ s_neigh,
    float* __restrict__ colsum,
    unsigned short* __restrict__ edges, int* __restrict__ degs) {
  __shared__ unsigned short sX[2][64 * 72];
  __shared__ unsigned short sW[2][64 * 72];
  __shared__ float sred[4][64];
  const int bid = blockIdx.x;
  const int tid = threadIdx.x;
  const int wid = tid >> 6, lane = tid & 63;

  if (bid >= GEMM_BLOCKS) {
    // ---- scan path: CSR build for row i
    const int i = bid - GEMM_BLOCKS;
    int* wave_tot = reinterpret_cast<int*>(&sred[0][0]);
    const float4* __restrict__ Arow4 =
        reinterpret_cast<const float4*>(A + (size_t)i * N_NODES);
    float4 v[4];
#pragma unroll
    for (int q = 0; q < 4; ++q) v[q] = Arow4[tid * 4 + q];
    int mask16 = 0;
#pragma unroll
    for (int q = 0; q < 4; ++q) {
      mask16 |= (v[q].x != 0.f) ? (1 << (q * 4 + 0)) : 0;
      mask16 |= (v[q].y != 0.f) ? (1 << (q * 4 + 1)) : 0;
      mask16 |= (v[q].z != 0.f) ? (1 << (q * 4 + 2)) : 0;
      mask16 |= (v[q].w != 0.f) ? (1 << (q * 4 + 3)) : 0;
    }
    int cnt = __popc(mask16);
    int inc = cnt;
#pragma unroll
    for (int s = 1; s < 64; s <<= 1) {
      int t = __shfl_up(inc, s, 64);
      if (lane >= s) inc += t;
    }
    if (lane == 63) wave_tot[wid] = inc;
    __syncthreads();
    int wprefix = 0, tot = 0;
#pragma unroll
    for (int w = 0; w < 4; ++w) {
      int t = wave_tot[w];
      if (w < wid) wprefix += t;
      tot += t;
    }
    int pos = wprefix + inc - cnt;
    const int jbase = tid * 16;
    unsigned short* __restrict__ erow = edges + (size_t)i * MAXE;
    while (mask16) {
      int k = __ffs(mask16) - 1;
      mask16 &= mask16 - 1;
      if (pos < MAXE) erow[pos] = (unsigned short)(jbase + k);
      ++pos;
    }
    if (tid == 0) degs[i] = tot < MAXE ? tot : MAXE;
    return;
  }

  // ---- GEMM path
  const int h = bid >> 6;
  const int n0 = (bid & 63) * 64;
  const int l15 = lane & 15, l4 = lane >> 4;

  const int row = tid >> 2, seg = (tid & 3) * 16;
  const float* xsrc = X + (size_t)(n0 + row) * F_IN + seg;
  const unsigned short* wsrc = WbT + ((size_t)h * FHD + row) * F_IN + seg;
  const int soff = row * 72 + seg;

  f32x4 acc[4];
#pragma unroll
  for (int j = 0; j < 4; ++j) acc[j] = (f32x4){0.f, 0.f, 0.f, 0.f};

  {
    float4 xa = *(const float4*)(xsrc);
    float4 xb = *(const float4*)(xsrc + 4);
    float4 xc = *(const float4*)(xsrc + 8);
    float4 xd = *(const float4*)(xsrc + 12);
    bf16x8 p0, p1;
    p0[0] = f2bf(xa.x); p0[1] = f2bf(xa.y); p0[2] = f2bf(xa.z); p0[3] = f2bf(xa.w);
    p0[4] = f2bf(xb.x); p0[5] = f2bf(xb.y); p0[6] = f2bf(xb.z); p0[7] = f2bf(xb.w);
    p1[0] = f2bf(xc.x); p1[1] = f2bf(xc.y); p1[2] = f2bf(xc.z); p1[3] = f2bf(xc.w);
    p1[4] = f2bf(xd.x); p1[5] = f2bf(xd.y); p1[6] = f2bf(xd.z); p1[7] = f2bf(xd.w);
    *(bf16x8*)&sX[0][soff] = p0;
    *(bf16x8*)&sX[0][soff + 8] = p1;
    *(bf16x8*)&sW[0][soff] = *(const bf16x8*)(wsrc);
    *(bf16x8*)&sW[0][soff + 8] = *(const bf16x8*)(wsrc + 8);
  }
  __syncthreads();

  int cur = 0;
  for (int s = 0; s < 8; ++s) {
    float4 xa, xb, xc, xd;
    bf16x8 pw0, pw1;
    const bool pf = (s < 7);
    if (pf) {
      const int k = (s + 1) * 64;
      xa = *(const float4*)(xsrc + k);
      xb = *(const float4*)(xsrc + k + 4);
      xc = *(const float4*)(xsrc + k + 8);
      xd = *(const float4*)(xsrc + k + 12);
      pw0 = *(const bf16x8*)(wsrc + k);
      pw1 = *(const bf16x8*)(wsrc + k + 8);
    }
#pragma unroll
    for (int kk = 0; kk < 2; ++kk) {
      bf16x8 a = *(const bf16x8*)&sX[cur][(wid * 16 + l15) * 72 + kk * 32 + l4 * 8];
#pragma unroll
      for (int tn = 0; tn < 4; ++tn) {
        bf16x8 b = *(const bf16x8*)&sW[cur][(tn * 16 + l15) * 72 + kk * 32 + l4 * 8];
        acc[tn] =
            __builtin_amdgcn_mfma_f32_16x16x32_bf16(a, b, acc[tn], 0, 0, 0);
      }
    }
    if (pf) {
      bf16x8 p0, p1;
      p0[0] = f2bf(xa.x); p0[1] = f2bf(xa.y); p0[2] = f2bf(xa.z); p0[3] = f2bf(xa.w);
      p0[4] = f2bf(xb.x); p0[5] = f2bf(xb.y); p0[6] = f2bf(xb.z); p0[7] = f2bf(xb.w);
      p1[0] = f2bf(xc.x); p1[1] = f2bf(xc.y); p1[2] = f2bf(xc.z); p1[3] = f2bf(xc.w);
      p1[4] = f2bf(xd.x); p1[5] = f2bf(xd.y); p1[6] = f2bf(xd.z); p1[7] = f2bf(xd.w);
      *(bf16x8*)&sX[cur ^ 1][soff] = p0;
      *(bf16x8*)&sX[cur ^ 1][soff + 8] = p1;
      *(bf16x8*)&sW[cur ^ 1][soff] = pw0;
      *(bf16x8*)&sW[cur ^ 1][soff + 8] = pw1;
      __syncthreads();
      cur ^= 1;
    }
  }

  float aS[4], aN[4];
#pragma unroll
  for (int tn = 0; tn < 4; ++tn) {
    aS[tn] = a_self[h * FHD + tn * 16 + l15];
    aN[tn] = a_neigh[h * FHD + tn * 16 + l15];
  }
#pragma unroll
  for (int r = 0; r < 4; ++r) {
    const int grow = n0 + wid * 16 + l4 * 4 + r;
#pragma unroll
    for (int tn = 0; tn < 4; ++tn)
      featsb[(size_t)grow * C_OUT + h * FHD + tn * 16 + l15] =
          f2bf(acc[tn][r]);
    float ps = 0.f, pn = 0.f;
#pragma unroll
    for (int tn = 0; tn < 4; ++tn) {
      float v = acc[tn][r];
      ps = fmaf(v, aS[tn], ps);
      pn = fmaf(v, aN[tn], pn);
    }
#pragma unroll
    for (int sh = 1; sh < 16; sh <<= 1) {
      ps += __shfl_xor(ps, sh, 64);
      pn += __shfl_xor(pn, sh, 64);
    }
    if (l15 == 0) {
      s_self[grow * 8 + h] = ps;
      s_neigh[grow * 8 + h] = pn;
    }
  }

  float psum[4];
#pragma unroll
  for (int tn = 0; tn < 4; ++tn) {
    float s = acc[tn][0] + acc[tn][1] + acc[tn][2] + acc[tn][3];
    s += __shfl_xor(s, 16, 64);
    s += __shfl_xor(s, 32, 64);
    psum[tn] = s;
  }
  __syncthreads();
  if (l4 == 0) {
#pragma unroll
    for (int tn = 0; tn < 4; ++tn) sred[wid][tn * 16 + l15] = psum[tn];
  }
  __syncthreads();
  if (tid < 64) {
    float s = sred[0][tid] + sred[1][tid] + sred[2][tid] + sred[3][tid];
    atomicAdd(&colsum[h * FHD + tid], s);
  }
}

// ---------------------------------------------------------------------------
// attn v9 (R18 verbatim): 256 thr/block, lane owns 8 cols (16B/edge), wave =
// edge quarter; gather math = v_dot2_f32_bf16 on edge pairs (weights packed
// bf16x2, columns interleaved via v_perm_b32); NT out stores.
// ---------------------------------------------------------------------------
__global__ __launch_bounds__(256) void attn_kernel(
    const unsigned short* __restrict__ edges, const int* __restrict__ degs,
    const unsigned short* __restrict__ featsb,
    const float* __restrict__ s_self, const float* __restrict__ s_neigh,
    const float* __restrict__ colsum, const float* __restrict__ bias,
    float* __restrict__ out) {
  const int i = blockIdx.x;
  const int tid = threadIdx.x;
  const int wid = tid >> 6, lane = tid & 63;
  __shared__ int s_idx[MAXE];
  __shared__ int s_off[MAXE];
  __shared__ float s_w[H_HEADS][MAXE_P];
  __shared__ float sh_self[8];
  __shared__ float sh_e0[8], sh_invZ[8];
  __shared__ float s_part[3][64][9];

  const int deg = degs[i];
  if (tid < 8) sh_self[tid] = s_self[i * 8 + tid];
  if (tid < deg) {
    int j = edges[(size_t)i * MAXE + tid];
    s_idx[tid] = j;
    s_off[tid] = j << 10;
  }
  __syncthreads();

  for (int k = tid; k < deg * 8; k += 256) {
    int e = k >> 3, h = k & 7;
    int j = s_idx[e];
    float l = sh_self[h] + s_neigh[j * 8 + h];
    s_w[h][e] = l > 0.f ? l : ALPHA * l;
  }
  __syncthreads();

#pragma unroll
  for (int p = 0; p < 2; ++p) {
    const int h = wid * 2 + p;
    float m = -1e30f;
    for (int e = lane; e < deg; e += 64) m = fmaxf(m, s_w[h][e]);
#pragma unroll
    for (int s = 32; s > 0; s >>= 1) m = fmaxf(m, __shfl_xor(m, s, 64));
    m = fmaxf(m, 0.0f);
    float e0 = __expf(-m);
    float zs = 0.f;
    for (int e = lane; e < deg; e += 64) {
      float w = __expf(s_w[h][e] - m);
      s_w[h][e] = w - e0;
      zs += w;
    }
#pragma unroll
    for (int s = 32; s > 0; s >>= 1) zs += __shfl_xor(zs, s, 64);
    if (lane == 0) {
      sh_e0[h] = e0;
      sh_invZ[h] = 1.0f / (zs + (float)(N_NODES - deg) * e0);
    }
  }
  __syncthreads();

  // Gather: co = column oct (8 cols, 16B), wave = edge quarter, edge pairs.
  const int co = lane;
  const int q = wid;
  const int h = co >> 3;
  const int dq = (deg + 3) >> 2;
  const int ebeg = q * dq;
  const int eend = (ebeg + dq) < deg ? (ebeg + dq) : deg;
  const char* __restrict__ fbase =
      reinterpret_cast<const char*>(featsb) + co * 16;
  float a0 = 0.f, a1 = 0.f, a2 = 0.f, a3 = 0.f;
  float a4 = 0.f, a5 = 0.f, a6 = 0.f, a7 = 0.f;
  float c0 = 0.f, c1 = 0.f, c2 = 0.f, c3 = 0.f;
  float c4 = 0.f, c5 = 0.f, c6 = 0.f, c7 = 0.f;

#define DOT2(accv, pair, wp) \
  asm("v_dot2_f32_bf16 %0, %1, %2, %0" : "+v"(accv) : "v"(pair), "v"(wp))

  int e = ebeg;
  for (; e + 3 < eend; e += 4) {
    float w0 = s_w[h][e], w1 = s_w[h][e + 1];
    float w2 = s_w[h][e + 2], w3 = s_w[h][e + 3];
    unsigned wp01, wp23;
    asm("v_cvt_pk_bf16_f32 %0, %1, %2" : "=v"(wp01) : "v"(w0), "v"(w1));
    asm("v_cvt_pk_bf16_f32 %0, %1, %2" : "=v"(wp23) : "v"(w2), "v"(w3));
    int o0 = s_off[e], o1 = s_off[e + 1];
    int o2 = s_off[e + 2], o3 = s_off[e + 3];
    uint4 u0 = *reinterpret_cast<const uint4*>(fbase + o0);
    uint4 u1 = *reinterpret_cast<const uint4*>(fbase + o1);
    uint4 u2 = *reinterpret_cast<const uint4*>(fbase + o2);
    uint4 u3 = *reinterpret_cast<const uint4*>(fbase + o3);
    // pair (e, e+1): low16s -> even col, high16s -> odd col
    unsigned plo, phi;
    plo = __builtin_amdgcn_perm(u1.x, u0.x, 0x05040100u);
    phi = __builtin_amdgcn_perm(u1.x, u0.x, 0x07060302u);
    DOT2(a0, plo, wp01); DOT2(a1, phi, wp01);
    plo = __builtin_amdgcn_perm(u1.y, u0.y, 0x05040100u);
    phi = __builtin_amdgcn_perm(u1.y, u0.y, 0x07060302u);
    DOT2(a2, plo, wp01); DOT2(a3, phi, wp01);
    plo = __builtin_amdgcn_perm(u1.z, u0.z, 0x05040100u);
    phi = __builtin_amdgcn_perm(u1.z, u0.z, 0x07060302u);
    DOT2(a4, plo, wp01); DOT2(a5, phi, wp01);
    plo = __builtin_amdgcn_perm(u1.w, u0.w, 0x05040100u);
    phi = __builtin_amdgcn_perm(u1.w, u0.w, 0x07060302u);
    DOT2(a6, plo, wp01); DOT2(a7, phi, wp01);
    // pair (e+2, e+3)
    plo = __builtin_amdgcn_perm(u3.x, u2.x, 0x05040100u);
    phi = __builtin_amdgcn_perm(u3.x, u2.x, 0x07060302u);
    DOT2(c0, plo, wp23); DOT2(c1, phi, wp23);
    plo = __builtin_amdgcn_perm(u3.y, u2.y, 0x05040100u);
    phi = __builtin_amdgcn_perm(u3.y, u2.y, 0x07060302u);
    DOT2(c2, plo, wp23); DOT2(c3, phi, wp23);
    plo = __builtin_amdgcn_perm(u3.z, u2.z, 0x05040100u);
    phi = __builtin_amdgcn_perm(u3.z, u2.z, 0x07060302u);
    DOT2(c4, plo, wp23); DOT2(c5, phi, wp23);
    plo = __builtin_amdgcn_perm(u3.w, u2.w, 0x05040100u);
    phi = __builtin_amdgcn_perm(u3.w, u2.w, 0x07060302u);
    DOT2(c6, plo, wp23); DOT2(c7, phi, wp23);
  }
  for (; e < eend; ++e) {  // scalar tail (exact f32 path)
    float w0 = s_w[h][e];
    uint4 u0 = *reinterpret_cast<const uint4*>(fbase + s_off[e]);
    a0 = fmaf(w0, __uint_as_float(u0.x << 16), a0);
    a1 = fmaf(w0, __uint_as_float(u0.x & 0xFFFF0000u), a1);
    a2 = fmaf(w0, __uint_as_float(u0.y << 16), a2);
    a3 = fmaf(w0, __uint_as_float(u0.y & 0xFFFF0000u), a3);
    a4 = fmaf(w0, __uint_as_float(u0.z << 16), a4);
    a5 = fmaf(w0, __uint_as_float(u0.z & 0xFFFF0000u), a5);
    a6 = fmaf(w0, __uint_as_float(u0.w << 16), a6);
    a7 = fmaf(w0, __uint_as_float(u0.w & 0xFFFF0000u), a7);
  }
#undef DOT2
  a0 += c0; a1 += c1; a2 += c2; a3 += c3;
  a4 += c4; a5 += c5; a6 += c6; a7 += c7;

  if (q > 0) {
    float* p = &s_part[q - 1][co][0];
    p[0] = a0; p[1] = a1; p[2] = a2; p[3] = a3;
    p[4] = a4; p[5] = a5; p[6] = a6; p[7] = a7;
  }
  __syncthreads();
  if (q == 0) {
#pragma unroll
    for (int pp = 0; pp < 3; ++pp) {
      const float* p = &s_part[pp][co][0];
      a0 += p[0]; a1 += p[1]; a2 += p[2]; a3 += p[3];
      a4 += p[4]; a5 += p[5]; a6 += p[6]; a7 += p[7];
    }
    const float e0 = sh_e0[h], invZ = sh_invZ[h];
    const float4 cs0 = *reinterpret_cast<const float4*>(&colsum[co * 8]);
    const float4 cs1 = *reinterpret_cast<const float4*>(&colsum[co * 8 + 4]);
    const float4 bb0 = *reinterpret_cast<const float4*>(&bias[co * 8]);
    const float4 bb1 = *reinterpret_cast<const float4*>(&bias[co * 8 + 4]);
    f32x4 o0, o1;
    float v;
    v = (a0 + e0 * cs0.x) * invZ + bb0.x; o0.x = v > 0.f ? v : 0.f;
    v = (a1 + e0 * cs0.y) * invZ + bb0.y; o0.y = v > 0.f ? v : 0.f;
    v = (a2 + e0 * cs0.z) * invZ + bb0.z; o0.z = v > 0.f ? v : 0.f;
    v = (a3 + e0 * cs0.w) * invZ + bb0.w; o0.w = v > 0.f ? v : 0.f;
    v = (a4 + e0 * cs1.x) * invZ + bb1.x; o1.x = v > 0.f ? v : 0.f;
    v = (a5 + e0 * cs1.y) * invZ + bb1.y; o1.y = v > 0.f ? v : 0.f;
    v = (a6 + e0 * cs1.z) * invZ + bb1.z; o1.z = v > 0.f ? v : 0.f;
    v = (a7 + e0 * cs1.w) * invZ + bb1.w; o1.w = v > 0.f ? v : 0.f;
    f32x4* dst = reinterpret_cast<f32x4*>(&out[(size_t)i * C_OUT + co * 8]);
    __builtin_nontemporal_store(o0, dst);
    __builtin_nontemporal_store(o1, dst + 1);
  }
}

extern "C" void kernel_launch(void* const* d_in, const int* in_sizes, int n_in,
                              void* d_out, int out_size, void* d_ws, size_t ws_size,
                              hipStream_t stream) {
  const float* X = (const float*)d_in[0];
  const float* A = (const float*)d_in[1];
  const float* W = (const float*)d_in[2];
  const float* a_self = (const float*)d_in[3];
  const float* a_neigh = (const float*)d_in[4];
  const float* b = (const float*)d_in[5];
  float* out = (float*)d_out;

  char* ws = (char*)d_ws;
  unsigned short* featsb = (unsigned short*)ws;               // 4 MB
  char* p = ws + (size_t)N_NODES * C_OUT * 2;
  float* s_self = (float*)p;  p += N_NODES * H_HEADS * 4;     // 128 KB
  float* s_neigh = (float*)p; p += N_NODES * H_HEADS * 4;     // 128 KB
  float* colsum = (float*)p;  p += C_OUT * 4;                 // 2 KB
  int* degs = (int*)p;        p += N_NODES * 4;               // 16 KB
  unsigned short* edges = (unsigned short*)p;
  p += (size_t)N_NODES * MAXE * 2;                            // 1.5 MB
  unsigned short* WbT = (unsigned short*)p;                   // 512 KB

  conv_kernel<<<65, 256, 0, stream>>>(W, WbT, colsum);
  gemm_scan_kernel<<<GEMM_BLOCKS + N_NODES, 256, 0, stream>>>(
      X, WbT, a_self, a_neigh, A, featsb, s_self, s_neigh, colsum, edges,
      degs);
  attn_kernel<<<N_NODES, 256, 0, stream>>>(edges, degs, featsb, s_self,
                                           s_neigh, colsum, b, out);
}